// Round 3
// baseline (1554.579 us; speedup 1.0000x reference)
//
#include <hip/hip_runtime.h>
#include <hip/hip_bf16.h>

constexpr int Kk = 27;
constexpr int Mm = 131072;
constexpr int Nn = 524288;
constexpr int Cc = 64;
constexpr float BN_EPS = 1e-5f;

typedef __attribute__((ext_vector_type(8))) short bf16x8;
typedef __attribute__((ext_vector_type(4))) float f32x4;
typedef __attribute__((ext_vector_type(8))) unsigned short ushort8v;

// ---------------- ws layout ----------------
// [0,512)      : stats (128 f32: sum | sumsq)
// [512,1024)   : ss (128 f32: scale | shift)
// [1024, +221184)  : W bf16 fragments (27 * 4096 ushort)
// MID : outb at 222208 (N*64 bf16)
// FULL: xb at 222208, outb at 222208 + 67108864
constexpr size_t WF_OFF = 1024;
constexpr size_t WF_BYTES = (size_t)Kk * 4096 * 2;      // 221184
constexpr size_t BUF0_OFF = WF_OFF + WF_BYTES;          // 222208 (16B aligned)
constexpr size_t ROWBUF_BYTES = (size_t)Nn * Cc * 2;    // 67108864
constexpr size_t WS_MID  = BUF0_OFF + ROWBUF_BYTES;     // 67331072 (known to fit)
constexpr size_t WS_FULL = BUF0_OFF + 2 * ROWBUF_BYTES; // 134439936

static __device__ __forceinline__ unsigned short f2bf(float f) {
    __hip_bfloat16 h = __float2bfloat16(f);
    return *reinterpret_cast<unsigned short*>(&h);
}
static __device__ __forceinline__ float bf2f(unsigned short u) {
    union { unsigned int i; float f; } v; v.i = ((unsigned int)u) << 16; return v.f;
}
static __device__ __forceinline__ unsigned int pk2(float a, float b) {
    return (unsigned int)f2bf(a) | ((unsigned int)f2bf(b) << 16);
}
static __device__ __forceinline__ void atomic_pk_bf16(unsigned short* p, unsigned int v) {
    asm volatile("global_atomic_pk_add_bf16 %0, %1, off"
                 :: "v"((unsigned long long)(uintptr_t)p), "v"(v) : "memory");
}

// ---------------- converts ----------------
__global__ __launch_bounds__(256) void convert_x_kernel(
    const float* __restrict__ x, unsigned short* __restrict__ xb)
{
    const size_t total4 = (size_t)Nn * Cc / 4;
    for (size_t i = (size_t)blockIdx.x * blockDim.x + threadIdx.x; i < total4;
         i += (size_t)gridDim.x * blockDim.x) {
        const float4 v = reinterpret_cast<const float4*>(x)[i];
        ushort4 o;
        o.x = f2bf(v.x); o.y = f2bf(v.y); o.z = f2bf(v.z); o.w = f2bf(v.w);
        reinterpret_cast<ushort4*>(xb)[i] = o;
    }
}

// Wf[((k*8 + ct*2 + kk)*64 + lane)*8 + j] = bf16( W[k][kk*32+(lane>>4)*8+j][ct*16+(lane&15)] )
__global__ __launch_bounds__(256) void convert_w_kernel(
    const float* __restrict__ W, unsigned short* __restrict__ Wf)
{
    const int t = blockIdx.x * blockDim.x + threadIdx.x;
    if (t >= Kk * 4096) return;
    const int j    = t & 7;
    const int lane = (t >> 3) & 63;
    const int kk   = (t >> 9) & 1;
    const int ct   = (t >> 10) & 3;
    const int k    = t >> 12;
    const int cin  = kk * 32 + ((lane >> 4) & 3) * 8 + j;
    const int cout = ct * 16 + (lane & 15);
    Wf[t] = f2bf(W[(size_t)k * 4096 + cin * 64 + cout]);
}

// ---------------- swapped-operand MFMA + pk-bf16 atomic scatter ----------------
// D = W^T x^T : a-operand = Wf frag (cout on lane&15, cin on (lane>>4)*8+j),
// b-operand = x frag (gathered row on lane&15, cin on (lane>>4)*8+j).
// D: col(lane&15) = gathered row, row((lane>>4)*4+reg) = cout within ct-tile
// -> lane holds 4 CONTIGUOUS channels ct*16+lgrp*4+{0..3} of out row outI[base+lrow].
constexpr int RPB2 = 256;
constexpr int BPK2 = Mm / RPB2;   // 512

template <bool HAS_XB>
__global__ __launch_bounds__(256) void scatter_pk_kernel(
    const float* __restrict__ x, const unsigned short* __restrict__ xb,
    const unsigned short* __restrict__ Wf,
    const int* __restrict__ in_idx, const int* __restrict__ out_idx,
    unsigned short* __restrict__ outb)
{
    const int tid  = threadIdx.x;
    const int lane = tid & 63;
    const int w    = tid >> 6;
    const int k     = blockIdx.x / BPK2;
    const int chunk = blockIdx.x % BPK2;
    const int m0    = chunk * RPB2 + w * 64;

    const int lrow = lane & 15;
    const int lgrp = lane >> 4;

    const unsigned short* Wk = Wf + (size_t)k * 4096;
    bf16x8 B[4][2];
#pragma unroll
    for (int ct = 0; ct < 4; ++ct)
#pragma unroll
        for (int kk = 0; kk < 2; ++kk)
            B[ct][kk] = *reinterpret_cast<const bf16x8*>(Wk + ((ct * 2 + kk) * 64 + lane) * 8);

    const int* inI  = in_idx  + (size_t)k * Mm + m0;
    const int* outI = out_idx + (size_t)k * Mm + m0;

#pragma unroll
    for (int rt = 0; rt < 4; ++rt) {
        const int base = rt * 16;
        const int ridx = inI[base + lrow];
        bf16x8 X0, X1;
        if (HAS_XB) {
            const unsigned short* xr = xb + (size_t)ridx * Cc + lgrp * 8;
            X0 = *reinterpret_cast<const bf16x8*>(xr);
            X1 = *reinterpret_cast<const bf16x8*>(xr + 32);
        } else {
            const float* xr = x + (size_t)ridx * Cc + lgrp * 8;
            const float4 a0 = *reinterpret_cast<const float4*>(xr);
            const float4 a1 = *reinterpret_cast<const float4*>(xr + 4);
            const float4 b0 = *reinterpret_cast<const float4*>(xr + 32);
            const float4 b1 = *reinterpret_cast<const float4*>(xr + 36);
            X0[0]=(short)f2bf(a0.x); X0[1]=(short)f2bf(a0.y); X0[2]=(short)f2bf(a0.z); X0[3]=(short)f2bf(a0.w);
            X0[4]=(short)f2bf(a1.x); X0[5]=(short)f2bf(a1.y); X0[6]=(short)f2bf(a1.z); X0[7]=(short)f2bf(a1.w);
            X1[0]=(short)f2bf(b0.x); X1[1]=(short)f2bf(b0.y); X1[2]=(short)f2bf(b0.z); X1[3]=(short)f2bf(b0.w);
            X1[4]=(short)f2bf(b1.x); X1[5]=(short)f2bf(b1.y); X1[6]=(short)f2bf(b1.z); X1[7]=(short)f2bf(b1.w);
        }
        const int oi = outI[base + lrow];

        f32x4 acc[4];
#pragma unroll
        for (int ct = 0; ct < 4; ++ct) {
            acc[ct] = __builtin_amdgcn_mfma_f32_16x16x32_bf16(
                B[ct][0], X0, (f32x4){0.f, 0.f, 0.f, 0.f}, 0, 0, 0);
            acc[ct] = __builtin_amdgcn_mfma_f32_16x16x32_bf16(
                B[ct][1], X1, acc[ct], 0, 0, 0);
        }

        unsigned short* orow = outb + (size_t)oi * Cc + lgrp * 4;
#pragma unroll
        for (int ct = 0; ct < 4; ++ct) {
            atomic_pk_bf16(orow + ct * 16,     pk2(acc[ct][0], acc[ct][1]));
            atomic_pk_bf16(orow + ct * 16 + 2, pk2(acc[ct][2], acc[ct][3]));
        }
    }
}

// ---------------- fp32 fallback (round-1 path) ----------------
constexpr int ROWS_PER_WAVE = 32;
constexpr int WAVES_PER_BLOCK = 4;
constexpr int ROWS_PER_BLOCK = ROWS_PER_WAVE * WAVES_PER_BLOCK;
constexpr int BLOCKS_PER_K = Mm / ROWS_PER_BLOCK;

__global__ __launch_bounds__(256) void scatter_gemm_kernel(
    const float* __restrict__ x, const float* __restrict__ W,
    const int* __restrict__ in_idx, const int* __restrict__ out_idx,
    float* __restrict__ out)
{
    const int tid  = threadIdx.x;
    const int lane = tid & 63;
    const int w    = tid >> 6;
    const int k     = blockIdx.x / BLOCKS_PER_K;
    const int chunk = blockIdx.x % BLOCKS_PER_K;
    const int m0    = chunk * ROWS_PER_BLOCK + w * ROWS_PER_WAVE;

    const float* Wk = W + k * (Cc * Cc);
    float wcol[Cc];
#pragma unroll
    for (int i = 0; i < Cc; ++i) wcol[i] = Wk[i * Cc + lane];

    const int* inI  = in_idx  + (size_t)k * Mm + m0;
    const int* outI = out_idx + (size_t)k * Mm + m0;

    __shared__ float xs[WAVES_PER_BLOCK][ROWS_PER_WAVE][Cc];

    for (int r = 0; r < ROWS_PER_WAVE; ++r)
        xs[w][r][lane] = x[(size_t)inI[r] * Cc + lane];

    for (int r = 0; r < ROWS_PER_WAVE; ++r) {
        const float* xr = &xs[w][r][0];
        float acc = 0.f;
#pragma unroll
        for (int i = 0; i < Cc; i += 4) {
            const float4 xv = *reinterpret_cast<const float4*>(xr + i);
            acc = fmaf(xv.x, wcol[i + 0], acc);
            acc = fmaf(xv.y, wcol[i + 1], acc);
            acc = fmaf(xv.z, wcol[i + 2], acc);
            acc = fmaf(xv.w, wcol[i + 3], acc);
        }
        atomicAdd(out + (size_t)outI[r] * Cc + lane, acc);
    }
}

__global__ __launch_bounds__(256) void bn_stats_f32(
    const float* __restrict__ out, float* __restrict__ stats)
{
    const int tid = threadIdx.x;
    const int c = tid & 63;
    const int g = tid >> 6;
    float s = 0.f, sq = 0.f;
    for (int r = blockIdx.x * 4 + g; r < Nn; r += gridDim.x * 4) {
        const float v = out[(size_t)r * Cc + c];
        s += v;
        sq = fmaf(v, v, sq);
    }
    __shared__ float lsum[4][64];
    __shared__ float lsq[4][64];
    lsum[g][c] = s;
    lsq[g][c]  = sq;
    __syncthreads();
    if (tid < 64) {
        atomicAdd(stats + c,      lsum[0][c] + lsum[1][c] + lsum[2][c] + lsum[3][c]);
        atomicAdd(stats + 64 + c, lsq[0][c] + lsq[1][c] + lsq[2][c] + lsq[3][c]);
    }
}

__global__ __launch_bounds__(256) void bn_apply_f32(
    float* __restrict__ out, const float* __restrict__ ss)
{
    const size_t total4 = (size_t)Nn * Cc / 4;
    const float4* ssc = reinterpret_cast<const float4*>(ss);
    float4* o4 = reinterpret_cast<float4*>(out);
    for (size_t i = (size_t)blockIdx.x * blockDim.x + threadIdx.x; i < total4;
         i += (size_t)gridDim.x * blockDim.x) {
        const int c4 = (int)(i & 15);
        const float4 sc = ssc[c4];
        const float4 sh = ssc[16 + c4];
        float4 v = o4[i];
        v.x = fmaxf(fmaf(v.x, sc.x, sh.x), 0.f);
        v.y = fmaxf(fmaf(v.y, sc.y, sh.y), 0.f);
        v.z = fmaxf(fmaf(v.z, sc.z, sh.z), 0.f);
        v.w = fmaxf(fmaf(v.w, sc.w, sh.w), 0.f);
        o4[i] = v;
    }
}

// ---------------- BN on bf16 buffer ----------------
// Lane reads ushort8 (8 channels); channel group fixed per thread since
// grid-stride is a multiple of 8 vec8s.
__global__ __launch_bounds__(256) void bn_stats_bf16(
    const unsigned short* __restrict__ outb, float* __restrict__ stats)
{
    const int tid = threadIdx.x;
    const int lane = tid & 63;
    const int w = tid >> 6;
    const size_t total8 = (size_t)Nn * Cc / 8;
    float s[8] = {0,0,0,0,0,0,0,0};
    float q[8] = {0,0,0,0,0,0,0,0};
    const ushort8v* p = reinterpret_cast<const ushort8v*>(outb);
    for (size_t i = (size_t)blockIdx.x * 256 + tid; i < total8;
         i += (size_t)gridDim.x * 256) {
        const ushort8v v = p[i];
#pragma unroll
        for (int j = 0; j < 8; ++j) {
            const float f = bf2f(v[j]);
            s[j] += f;
            q[j] = fmaf(f, f, q[j]);
        }
    }
    // combine lanes with the same (lane & 7): xor 8,16,32
#pragma unroll
    for (int off = 8; off < 64; off <<= 1) {
#pragma unroll
        for (int j = 0; j < 8; ++j) {
            s[j] += __shfl_xor(s[j], off, 64);
            q[j] += __shfl_xor(q[j], off, 64);
        }
    }
    __shared__ float ls[4][8][8];
    __shared__ float lq[4][8][8];
    if (lane < 8) {
#pragma unroll
        for (int j = 0; j < 8; ++j) { ls[w][lane][j] = s[j]; lq[w][lane][j] = q[j]; }
    }
    __syncthreads();
    if (tid < 64) {
        const int g = tid >> 3, j = tid & 7;
        const float ts = ls[0][g][j] + ls[1][g][j] + ls[2][g][j] + ls[3][g][j];
        const float tq = lq[0][g][j] + lq[1][g][j] + lq[2][g][j] + lq[3][g][j];
        atomicAdd(stats + tid, ts);
        atomicAdd(stats + 64 + tid, tq);
    }
}

__global__ void bn_finalize_kernel(const float* __restrict__ stats,
                                   const float* __restrict__ gamma,
                                   const float* __restrict__ beta,
                                   float* __restrict__ ss)
{
    const int c = threadIdx.x;
    const float inv_n = 1.f / (float)Nn;
    const float mean = stats[c] * inv_n;
    const float var  = stats[64 + c] * inv_n - mean * mean;
    const float scale = gamma[c] * rsqrtf(var + BN_EPS);
    ss[c]      = scale;
    ss[64 + c] = beta[c] - mean * scale;
}

__global__ __launch_bounds__(256) void bn_apply_bf16(
    const unsigned short* __restrict__ outb, const float* __restrict__ ss,
    float* __restrict__ out)
{
    const int tid = threadIdx.x;
    const int cg = (tid & 7) * 8;   // this thread always handles channels cg..cg+7
    float sc[8], sh[8];
#pragma unroll
    for (int j = 0; j < 8; ++j) { sc[j] = ss[cg + j]; sh[j] = ss[64 + cg + j]; }
    const size_t total8 = (size_t)Nn * Cc / 8;
    const ushort8v* p = reinterpret_cast<const ushort8v*>(outb);
    float4* o4 = reinterpret_cast<float4*>(out);
    for (size_t i = (size_t)blockIdx.x * 256 + tid; i < total8;
         i += (size_t)gridDim.x * 256) {
        const ushort8v v = p[i];
        float4 lo, hi;
        lo.x = fmaxf(fmaf(bf2f(v[0]), sc[0], sh[0]), 0.f);
        lo.y = fmaxf(fmaf(bf2f(v[1]), sc[1], sh[1]), 0.f);
        lo.z = fmaxf(fmaf(bf2f(v[2]), sc[2], sh[2]), 0.f);
        lo.w = fmaxf(fmaf(bf2f(v[3]), sc[3], sh[3]), 0.f);
        hi.x = fmaxf(fmaf(bf2f(v[4]), sc[4], sh[4]), 0.f);
        hi.y = fmaxf(fmaf(bf2f(v[5]), sc[5], sh[5]), 0.f);
        hi.z = fmaxf(fmaf(bf2f(v[6]), sc[6], sh[6]), 0.f);
        hi.w = fmaxf(fmaf(bf2f(v[7]), sc[7], sh[7]), 0.f);
        o4[i * 2]     = lo;
        o4[i * 2 + 1] = hi;
    }
}

extern "C" void kernel_launch(void* const* d_in, const int* in_sizes, int n_in,
                              void* d_out, int out_size, void* d_ws, size_t ws_size,
                              hipStream_t stream) {
    const float* x      = (const float*)d_in[0];
    const float* W      = (const float*)d_in[1];
    const float* gamma  = (const float*)d_in[2];
    const float* beta   = (const float*)d_in[3];
    const int*   in_idx = (const int*)d_in[4];
    const int*   out_idx= (const int*)d_in[5];
    float* out   = (float*)d_out;
    char*  ws    = (char*)d_ws;
    float* stats = (float*)ws;
    float* ss    = stats + 128;

    hipMemsetAsync(d_ws, 0, 256 * sizeof(float), stream);

    if (ws_size >= WS_MID) {
        unsigned short* Wf = (unsigned short*)(ws + WF_OFF);
        const bool full = (ws_size >= WS_FULL);
        unsigned short* xb   = (unsigned short*)(ws + BUF0_OFF);
        unsigned short* outb = full ? (unsigned short*)(ws + BUF0_OFF + ROWBUF_BYTES)
                                    : (unsigned short*)(ws + BUF0_OFF);

        hipMemsetAsync(outb, 0, ROWBUF_BYTES, stream);
        convert_w_kernel<<<(Kk * 4096 + 255) / 256, 256, 0, stream>>>(W, Wf);
        if (full) {
            convert_x_kernel<<<4096, 256, 0, stream>>>(x, xb);
            scatter_pk_kernel<true><<<Kk * BPK2, 256, 0, stream>>>(
                x, xb, Wf, in_idx, out_idx, outb);
        } else {
            scatter_pk_kernel<false><<<Kk * BPK2, 256, 0, stream>>>(
                x, nullptr, Wf, in_idx, out_idx, outb);
        }
        bn_stats_bf16<<<1024, 256, 0, stream>>>(outb, stats);
        bn_finalize_kernel<<<1, 64, 0, stream>>>(stats, gamma, beta, ss);
        bn_apply_bf16<<<2048, 256, 0, stream>>>(outb, ss, out);
    } else {
        hipMemsetAsync(d_out, 0, (size_t)Nn * Cc * sizeof(float), stream);
        scatter_gemm_kernel<<<Kk * BLOCKS_PER_K, 256, 0, stream>>>(x, W, in_idx, out_idx, out);
        bn_stats_f32<<<1024, 256, 0, stream>>>(out, stats);
        bn_finalize_kernel<<<1, 64, 0, stream>>>(stats, gamma, beta, ss);
        bn_apply_f32<<<4096, 256, 0, stream>>>(out, ss);
    }
}

// Round 4
// 478.996 us; speedup vs baseline: 3.2455x; 3.2455x over previous
//
#include <hip/hip_runtime.h>
#include <hip/hip_bf16.h>

constexpr int Kk = 27;
constexpr int Mm = 131072;
constexpr int Nn = 524288;
constexpr int Cc = 64;
constexpr float BN_EPS = 1e-5f;

typedef __attribute__((ext_vector_type(8))) short bf16x8;
typedef __attribute__((ext_vector_type(4))) float f32x4;
typedef __attribute__((ext_vector_type(8))) unsigned short ushort8v;

// ---------------- ws layout ----------------
constexpr size_t WF_OFF = 1024;
constexpr size_t WF_BYTES = (size_t)Kk * 4096 * 2;      // 221184
constexpr size_t BUF0_OFF = WF_OFF + WF_BYTES;          // 222208 (128B aligned)
constexpr size_t ROWBUF_BYTES = (size_t)Nn * Cc * 2;    // 67108864
constexpr size_t WS_MID  = BUF0_OFF + ROWBUF_BYTES;
constexpr size_t WS_FULL = BUF0_OFF + 2 * ROWBUF_BYTES;

static __device__ __forceinline__ unsigned short f2bf(float f) {
    __hip_bfloat16 h = __float2bfloat16(f);
    return *reinterpret_cast<unsigned short*>(&h);
}
static __device__ __forceinline__ float bf2f(unsigned short u) {
    union { unsigned int i; float f; } v; v.i = ((unsigned int)u) << 16; return v.f;
}
static __device__ __forceinline__ unsigned int pk2(float a, float b) {
    return (unsigned int)f2bf(a) | ((unsigned int)f2bf(b) << 16);
}
static __device__ __forceinline__ void atomic_pk_bf16(unsigned short* p, unsigned int v) {
    asm volatile("global_atomic_pk_add_bf16 %0, %1, off"
                 :: "v"((unsigned long long)(uintptr_t)p), "v"(v) : "memory");
}

// ---------------- converts ----------------
__global__ __launch_bounds__(256) void convert_x_kernel(
    const float* __restrict__ x, unsigned short* __restrict__ xb)
{
    const size_t total4 = (size_t)Nn * Cc / 4;
    for (size_t i = (size_t)blockIdx.x * blockDim.x + threadIdx.x; i < total4;
         i += (size_t)gridDim.x * blockDim.x) {
        const float4 v = reinterpret_cast<const float4*>(x)[i];
        ushort4 o;
        o.x = f2bf(v.x); o.y = f2bf(v.y); o.z = f2bf(v.z); o.w = f2bf(v.w);
        reinterpret_cast<ushort4*>(xb)[i] = o;
    }
}

// Wf[((k*8 + ct*2 + kk)*64 + lane)*8 + j] = bf16( W[k][kk*32+(lane>>4)*8+j][ct*16+(lane&15)] )
__global__ __launch_bounds__(256) void convert_w_kernel(
    const float* __restrict__ W, unsigned short* __restrict__ Wf)
{
    const int t = blockIdx.x * blockDim.x + threadIdx.x;
    if (t >= Kk * 4096) return;
    const int j    = t & 7;
    const int lane = (t >> 3) & 63;
    const int kk   = (t >> 9) & 1;
    const int ct   = (t >> 10) & 3;
    const int k    = t >> 12;
    const int cin  = kk * 32 + ((lane >> 4) & 3) * 8 + j;
    const int cout = ct * 16 + (lane & 15);
    Wf[t] = f2bf(W[(size_t)k * 4096 + cin * 64 + cout]);
}

// ---------------- swapped-operand MFMA + full-line pk-bf16 scatter ----------------
// D = W^T x^T : lane holds channels ct*16+lgrp*4+{0..3} of out row outI[base+lrow].
// Bounce through wave-private LDS tile -> re-read row-major so 32 consecutive
// lanes cover one full 128B output row; each pk-atomic instruction then covers
// 2 rows = 4 fully-written 64B lines (the structural minimum).
constexpr int RPB2 = 256;
constexpr int BPK2 = Mm / RPB2;   // 512
constexpr int TPAD = 68;          // row stride in ushorts (pad 64 -> 68)

template <bool HAS_XB>
__global__ __launch_bounds__(256) void scatter_pk_kernel(
    const float* __restrict__ x, const unsigned short* __restrict__ xb,
    const unsigned short* __restrict__ Wf,
    const int* __restrict__ in_idx, const int* __restrict__ out_idx,
    unsigned short* __restrict__ outb)
{
    const int tid  = threadIdx.x;
    const int lane = tid & 63;
    const int w    = tid >> 6;
    const int k     = blockIdx.x / BPK2;
    const int chunk = blockIdx.x % BPK2;
    const int m0    = chunk * RPB2 + w * 64;

    const int lrow = lane & 15;
    const int lgrp = lane >> 4;
    const int hi   = lane >> 5;     // 0/1
    const int cpr  = lane & 31;     // channel-pair within row

    __shared__ unsigned short tile[4][2][16][TPAD];   // per-wave double-buffered

    const unsigned short* Wk = Wf + (size_t)k * 4096;
    bf16x8 B[4][2];
#pragma unroll
    for (int ct = 0; ct < 4; ++ct)
#pragma unroll
        for (int kk = 0; kk < 2; ++kk)
            B[ct][kk] = *reinterpret_cast<const bf16x8*>(Wk + ((ct * 2 + kk) * 64 + lane) * 8);

    const int* inI  = in_idx  + (size_t)k * Mm + m0;
    const int* outI = out_idx + (size_t)k * Mm + m0;

#pragma unroll
    for (int rt = 0; rt < 4; ++rt) {
        const int base = rt * 16;
        const int ridx = inI[base + lrow];
        bf16x8 X0, X1;
        if (HAS_XB) {
            const unsigned short* xr = xb + (size_t)ridx * Cc + lgrp * 8;
            X0 = *reinterpret_cast<const bf16x8*>(xr);
            X1 = *reinterpret_cast<const bf16x8*>(xr + 32);
        } else {
            const float* xr = x + (size_t)ridx * Cc + lgrp * 8;
            const float4 a0 = *reinterpret_cast<const float4*>(xr);
            const float4 a1 = *reinterpret_cast<const float4*>(xr + 4);
            const float4 b0 = *reinterpret_cast<const float4*>(xr + 32);
            const float4 b1 = *reinterpret_cast<const float4*>(xr + 36);
            X0[0]=(short)f2bf(a0.x); X0[1]=(short)f2bf(a0.y); X0[2]=(short)f2bf(a0.z); X0[3]=(short)f2bf(a0.w);
            X0[4]=(short)f2bf(a1.x); X0[5]=(short)f2bf(a1.y); X0[6]=(short)f2bf(a1.z); X0[7]=(short)f2bf(a1.w);
            X1[0]=(short)f2bf(b0.x); X1[1]=(short)f2bf(b0.y); X1[2]=(short)f2bf(b0.z); X1[3]=(short)f2bf(b0.w);
            X1[4]=(short)f2bf(b1.x); X1[5]=(short)f2bf(b1.y); X1[6]=(short)f2bf(b1.z); X1[7]=(short)f2bf(b1.w);
        }
        const int oi = outI[base + lrow];

        f32x4 acc[4];
#pragma unroll
        for (int ct = 0; ct < 4; ++ct) {
            acc[ct] = __builtin_amdgcn_mfma_f32_16x16x32_bf16(
                B[ct][0], X0, (f32x4){0.f, 0.f, 0.f, 0.f}, 0, 0, 0);
            acc[ct] = __builtin_amdgcn_mfma_f32_16x16x32_bf16(
                B[ct][1], X1, acc[ct], 0, 0, 0);
        }

        // stage this wave's 16x64 bf16 result tile (wave-private, no barrier)
        const int buf = rt & 1;
#pragma unroll
        for (int ct = 0; ct < 4; ++ct) {
            uint2 pv;
            pv.x = pk2(acc[ct][0], acc[ct][1]);
            pv.y = pk2(acc[ct][2], acc[ct][3]);
            *reinterpret_cast<uint2*>(&tile[w][buf][lrow][ct * 16 + lgrp * 4]) = pv;
        }

        // row-major re-read: instruction j covers rows 2j,2j+1 fully
        const unsigned int* tdw = reinterpret_cast<const unsigned int*>(&tile[w][buf][0][0]);
#pragma unroll
        for (int j = 0; j < 8; ++j) {
            const int row = 2 * j + hi;
            const unsigned int v = tdw[row * (TPAD / 2) + cpr];
            const int roi = __shfl(oi, row, 64);
            atomic_pk_bf16(outb + (size_t)roi * Cc + cpr * 2, v);
        }
    }
}

// ---------------- fp32 fallback (round-1 path) ----------------
constexpr int ROWS_PER_WAVE = 32;
constexpr int WAVES_PER_BLOCK = 4;
constexpr int ROWS_PER_BLOCK = ROWS_PER_WAVE * WAVES_PER_BLOCK;
constexpr int BLOCKS_PER_K = Mm / ROWS_PER_BLOCK;

__global__ __launch_bounds__(256) void scatter_gemm_kernel(
    const float* __restrict__ x, const float* __restrict__ W,
    const int* __restrict__ in_idx, const int* __restrict__ out_idx,
    float* __restrict__ out)
{
    const int tid  = threadIdx.x;
    const int lane = tid & 63;
    const int w    = tid >> 6;
    const int k     = blockIdx.x / BLOCKS_PER_K;
    const int chunk = blockIdx.x % BLOCKS_PER_K;
    const int m0    = chunk * ROWS_PER_BLOCK + w * ROWS_PER_WAVE;

    const float* Wk = W + k * (Cc * Cc);
    float wcol[Cc];
#pragma unroll
    for (int i = 0; i < Cc; ++i) wcol[i] = Wk[i * Cc + lane];

    const int* inI  = in_idx  + (size_t)k * Mm + m0;
    const int* outI = out_idx + (size_t)k * Mm + m0;

    __shared__ float xs[WAVES_PER_BLOCK][ROWS_PER_WAVE][Cc];

    for (int r = 0; r < ROWS_PER_WAVE; ++r)
        xs[w][r][lane] = x[(size_t)inI[r] * Cc + lane];

    for (int r = 0; r < ROWS_PER_WAVE; ++r) {
        const float* xr = &xs[w][r][0];
        float acc = 0.f;
#pragma unroll
        for (int i = 0; i < Cc; i += 4) {
            const float4 xv = *reinterpret_cast<const float4*>(xr + i);
            acc = fmaf(xv.x, wcol[i + 0], acc);
            acc = fmaf(xv.y, wcol[i + 1], acc);
            acc = fmaf(xv.z, wcol[i + 2], acc);
            acc = fmaf(xv.w, wcol[i + 3], acc);
        }
        atomicAdd(out + (size_t)outI[r] * Cc + lane, acc);
    }
}

__global__ __launch_bounds__(256) void bn_stats_f32(
    const float* __restrict__ out, float* __restrict__ stats)
{
    const int tid = threadIdx.x;
    const int c = tid & 63;
    const int g = tid >> 6;
    float s = 0.f, sq = 0.f;
    for (int r = blockIdx.x * 4 + g; r < Nn; r += gridDim.x * 4) {
        const float v = out[(size_t)r * Cc + c];
        s += v;
        sq = fmaf(v, v, sq);
    }
    __shared__ float lsum[4][64];
    __shared__ float lsq[4][64];
    lsum[g][c] = s;
    lsq[g][c]  = sq;
    __syncthreads();
    if (tid < 64) {
        atomicAdd(stats + c,      lsum[0][c] + lsum[1][c] + lsum[2][c] + lsum[3][c]);
        atomicAdd(stats + 64 + c, lsq[0][c] + lsq[1][c] + lsq[2][c] + lsq[3][c]);
    }
}

__global__ __launch_bounds__(256) void bn_apply_f32(
    float* __restrict__ out, const float* __restrict__ ss)
{
    const size_t total4 = (size_t)Nn * Cc / 4;
    const float4* ssc = reinterpret_cast<const float4*>(ss);
    float4* o4 = reinterpret_cast<float4*>(out);
    for (size_t i = (size_t)blockIdx.x * blockDim.x + threadIdx.x; i < total4;
         i += (size_t)gridDim.x * blockDim.x) {
        const int c4 = (int)(i & 15);
        const float4 sc = ssc[c4];
        const float4 sh = ssc[16 + c4];
        float4 v = o4[i];
        v.x = fmaxf(fmaf(v.x, sc.x, sh.x), 0.f);
        v.y = fmaxf(fmaf(v.y, sc.y, sh.y), 0.f);
        v.z = fmaxf(fmaf(v.z, sc.z, sh.z), 0.f);
        v.w = fmaxf(fmaf(v.w, sc.w, sh.w), 0.f);
        o4[i] = v;
    }
}

// ---------------- BN on bf16 buffer ----------------
__global__ __launch_bounds__(256) void bn_stats_bf16(
    const unsigned short* __restrict__ outb, float* __restrict__ stats)
{
    const int tid = threadIdx.x;
    const int lane = tid & 63;
    const int w = tid >> 6;
    const size_t total8 = (size_t)Nn * Cc / 8;
    float s[8] = {0,0,0,0,0,0,0,0};
    float q[8] = {0,0,0,0,0,0,0,0};
    const ushort8v* p = reinterpret_cast<const ushort8v*>(outb);
    for (size_t i = (size_t)blockIdx.x * 256 + tid; i < total8;
         i += (size_t)gridDim.x * 256) {
        const ushort8v v = p[i];
#pragma unroll
        for (int j = 0; j < 8; ++j) {
            const float f = bf2f(v[j]);
            s[j] += f;
            q[j] = fmaf(f, f, q[j]);
        }
    }
#pragma unroll
    for (int off = 8; off < 64; off <<= 1) {
#pragma unroll
        for (int j = 0; j < 8; ++j) {
            s[j] += __shfl_xor(s[j], off, 64);
            q[j] += __shfl_xor(q[j], off, 64);
        }
    }
    __shared__ float ls[4][8][8];
    __shared__ float lq[4][8][8];
    if (lane < 8) {
#pragma unroll
        for (int j = 0; j < 8; ++j) { ls[w][lane][j] = s[j]; lq[w][lane][j] = q[j]; }
    }
    __syncthreads();
    if (tid < 64) {
        const int g = tid >> 3, j = tid & 7;
        const float ts = ls[0][g][j] + ls[1][g][j] + ls[2][g][j] + ls[3][g][j];
        const float tq = lq[0][g][j] + lq[1][g][j] + lq[2][g][j] + lq[3][g][j];
        atomicAdd(stats + tid, ts);
        atomicAdd(stats + 64 + tid, tq);
    }
}

__global__ void bn_finalize_kernel(const float* __restrict__ stats,
                                   const float* __restrict__ gamma,
                                   const float* __restrict__ beta,
                                   float* __restrict__ ss)
{
    const int c = threadIdx.x;
    const float inv_n = 1.f / (float)Nn;
    const float mean = stats[c] * inv_n;
    const float var  = stats[64 + c] * inv_n - mean * mean;
    const float scale = gamma[c] * rsqrtf(var + BN_EPS);
    ss[c]      = scale;
    ss[64 + c] = beta[c] - mean * scale;
}

__global__ __launch_bounds__(256) void bn_apply_bf16(
    const unsigned short* __restrict__ outb, const float* __restrict__ ss,
    float* __restrict__ out)
{
    const int tid = threadIdx.x;
    const int cg = (tid & 7) * 8;
    float sc[8], sh[8];
#pragma unroll
    for (int j = 0; j < 8; ++j) { sc[j] = ss[cg + j]; sh[j] = ss[64 + cg + j]; }
    const size_t total8 = (size_t)Nn * Cc / 8;
    const ushort8v* p = reinterpret_cast<const ushort8v*>(outb);
    float4* o4 = reinterpret_cast<float4*>(out);
    for (size_t i = (size_t)blockIdx.x * 256 + tid; i < total8;
         i += (size_t)gridDim.x * 256) {
        const ushort8v v = p[i];
        float4 lo, hi;
        lo.x = fmaxf(fmaf(bf2f(v[0]), sc[0], sh[0]), 0.f);
        lo.y = fmaxf(fmaf(bf2f(v[1]), sc[1], sh[1]), 0.f);
        lo.z = fmaxf(fmaf(bf2f(v[2]), sc[2], sh[2]), 0.f);
        lo.w = fmaxf(fmaf(bf2f(v[3]), sc[3], sh[3]), 0.f);
        hi.x = fmaxf(fmaf(bf2f(v[4]), sc[4], sh[4]), 0.f);
        hi.y = fmaxf(fmaf(bf2f(v[5]), sc[5], sh[5]), 0.f);
        hi.z = fmaxf(fmaf(bf2f(v[6]), sc[6], sh[6]), 0.f);
        hi.w = fmaxf(fmaf(bf2f(v[7]), sc[7], sh[7]), 0.f);
        o4[i * 2]     = lo;
        o4[i * 2 + 1] = hi;
    }
}

extern "C" void kernel_launch(void* const* d_in, const int* in_sizes, int n_in,
                              void* d_out, int out_size, void* d_ws, size_t ws_size,
                              hipStream_t stream) {
    const float* x      = (const float*)d_in[0];
    const float* W      = (const float*)d_in[1];
    const float* gamma  = (const float*)d_in[2];
    const float* beta   = (const float*)d_in[3];
    const int*   in_idx = (const int*)d_in[4];
    const int*   out_idx= (const int*)d_in[5];
    float* out   = (float*)d_out;
    char*  ws    = (char*)d_ws;
    float* stats = (float*)ws;
    float* ss    = stats + 128;

    hipMemsetAsync(d_ws, 0, 256 * sizeof(float), stream);

    if (ws_size >= WS_MID) {
        unsigned short* Wf = (unsigned short*)(ws + WF_OFF);
        const bool full = (ws_size >= WS_FULL);
        unsigned short* xb   = (unsigned short*)(ws + BUF0_OFF);
        unsigned short* outb = full ? (unsigned short*)(ws + BUF0_OFF + ROWBUF_BYTES)
                                    : (unsigned short*)(ws + BUF0_OFF);

        hipMemsetAsync(outb, 0, ROWBUF_BYTES, stream);
        convert_w_kernel<<<(Kk * 4096 + 255) / 256, 256, 0, stream>>>(W, Wf);
        if (full) {
            convert_x_kernel<<<4096, 256, 0, stream>>>(x, xb);
            scatter_pk_kernel<true><<<Kk * BPK2, 256, 0, stream>>>(
                x, xb, Wf, in_idx, out_idx, outb);
        } else {
            scatter_pk_kernel<false><<<Kk * BPK2, 256, 0, stream>>>(
                x, nullptr, Wf, in_idx, out_idx, outb);
        }
        bn_stats_bf16<<<1024, 256, 0, stream>>>(outb, stats);
        bn_finalize_kernel<<<1, 64, 0, stream>>>(stats, gamma, beta, ss);
        bn_apply_bf16<<<2048, 256, 0, stream>>>(outb, ss, out);
    } else {
        hipMemsetAsync(d_out, 0, (size_t)Nn * Cc * sizeof(float), stream);
        scatter_gemm_kernel<<<Kk * BLOCKS_PER_K, 256, 0, stream>>>(x, W, in_idx, out_idx, out);
        bn_stats_f32<<<1024, 256, 0, stream>>>(out, stats);
        bn_finalize_kernel<<<1, 64, 0, stream>>>(stats, gamma, beta, ss);
        bn_apply_f32<<<4096, 256, 0, stream>>>(out, ss);
    }
}